// Round 7
// baseline (385.315 us; speedup 1.0000x reference)
//
#include <hip/hip_runtime.h>
#include <hip/hip_bf16.h>
#include <math.h>

#define N_NODES 8192
#define N_EDGES 131072
#define NGRP 16
#define NLAY 2
#define NELM 4
constexpr float INV_AVG = 1.0f / 16.0f;
constexpr float PI_F = 3.14159265358979323846f;

// converted fp32 buffer layout (element offsets)
#define CV_POS   0        // 24576
#define CV_EMB   24576    // 256
#define CV_R1    24832    // 1024  (natural [l][k:8][n:64])
#define CV_R2    25856    // 8192  (natural [l][k:64][n:64])
#define CV_R3    34048    // 8192  (natural [l][k:64][n:64])
#define CV_SC    42240    // 32768 (TRANSPOSED per (l,ty): [d:64][c:64])
#define CV_PROD  75008    // 32
#define CV_RO0   75040    // 64
#define CV_RO1A  75104    // 1024
#define CV_RO1B  76128    // 16
#define CVT_N    76144

// swizzled bf16 MFMA B-fragment weight buffer: per layer 10240 shorts
#define SWZ_PER_L 10240
#define SWZ_N     20480

typedef __hip_bfloat16 bf16;
typedef __attribute__((ext_vector_type(8))) short bf16x8;
typedef __attribute__((ext_vector_type(4))) float f32x4;

__device__ __forceinline__ float silu_f(float x){ return x / (1.0f + __expf(-x)); }
__device__ __forceinline__ float bfbits2f(unsigned short u){
  return __uint_as_float(((unsigned)u) << 16);
}
__device__ __forceinline__ short f2bs(float v){
  union { bf16 b; short s; } u; u.b = __float2bfloat16(v); return u.s;
}
// dtype-agnostic element load: flag==1 -> buffer is bf16, else fp32
__device__ __forceinline__ float ldf(const void* p, int i, int flag){
  if (flag) return bfbits2f(((const unsigned short*)p)[i]);
  return ((const float*)p)[i];
}

// ---------------- input dtype detection (1 wave) ----------------
__global__ void k_detect(const void* __restrict__ pos, int* __restrict__ flag){
  int t = threadIdx.x;  // 64 lanes
  const unsigned short* u = (const unsigned short*)pos;
  float va = bfbits2f(u[2*t]), vb = bfbits2f(u[2*t+1]);
  bool bad = !(fabsf(va) <= 1000.0f) || !(fabsf(vb) <= 1000.0f);
  unsigned long long m = __ballot(bad);
  if (t == 0) *flag = (m != 0ull) ? 0 : 1;
}

// ---------------- convert all float inputs to fp32 ws copies ----------------
// Wsc is stored TRANSPOSED per (layer,type): dst[(l*4+ty)*4096 + d*64 + c] = src[l][ty][c][d]
__global__ void k_cvt(const void* __restrict__ pos, const void* __restrict__ Wemb,
                      const void* __restrict__ Wr1, const void* __restrict__ Wr2,
                      const void* __restrict__ Wr3, const void* __restrict__ Wsc,
                      const void* __restrict__ wprod, const void* __restrict__ wro0,
                      const void* __restrict__ Wro1a, const void* __restrict__ wro1b,
                      const int* __restrict__ flag, float* __restrict__ cv){
  int i = blockIdx.x * 256 + threadIdx.x;
  int fl = *flag;
  if (i < 24576){ cv[CV_POS + i] = ldf(pos, i, fl); return; }
  if (i < 24832){ int j = i - 24576; cv[CV_EMB + j] = ldf(Wemb, j, fl); return; }
  if (i < 25856){ int j = i - 24832; cv[CV_R1  + j] = ldf(Wr1,  j, fl); return; }
  if (i < 34048){ int j = i - 25856; cv[CV_R2  + j] = ldf(Wr2,  j, fl); return; }
  if (i < 42240){ int j = i - 34048; cv[CV_R3  + j] = ldf(Wr3,  j, fl); return; }
  if (i < 75008){
    int j = i - 42240;                  // [lt:8][c:64][d:64]
    int lt = j >> 12, rem = j & 4095, c = rem >> 6, d = rem & 63;
    cv[CV_SC + lt*4096 + d*64 + c] = ldf(Wsc, j, fl); return;
  }
  if (i < 75040){ int j = i - 75008; cv[CV_PROD+ j] = ldf(wprod,j, fl); return; }
  if (i < 75104){ int j = i - 75040; cv[CV_RO0 + j] = ldf(wro0, j, fl); return; }
  if (i < 76128){ int j = i - 75104; cv[CV_RO1A+ j] = ldf(Wro1a,j, fl); return; }
  if (i < CVT_N){ int j = i - 76128; cv[CV_RO1B+ j] = ldf(wro1b,j, fl); return; }
}

// ---------------- build MFMA B-fragment-order bf16 weights ----------------
__global__ void k_swz(const float* __restrict__ cv, short* __restrict__ swz){
  int i = blockIdx.x * 256 + threadIdx.x;   // 20480 exact
  int l = i / SWZ_PER_L, w = i % SWZ_PER_L;
  float v;
  if (w < 2048){
    int t = w >> 9, q = (w >> 7) & 3, n = (w >> 3) & 15, j = w & 7;
    int k = q*8 + j;
    v = (k < 8) ? cv[CV_R1 + l*512 + k*64 + t*16 + n] : 0.0f;
  } else if (w < 6144){
    int w2 = w - 2048;
    int nt = w2 >> 10, kt = (w2 >> 9) & 1, q = (w2 >> 7) & 3, n = (w2 >> 3) & 15, j = w2 & 7;
    int k = kt*32 + q*8 + j;
    v = cv[CV_R2 + l*4096 + k*64 + nt*16 + n];
  } else {
    int w3 = w - 6144;
    int nt = w3 >> 10, kt = (w3 >> 9) & 1, q = (w3 >> 7) & 3, n = (w3 >> 3) & 15, j = w3 & 7;
    int k = kt*32 + q*8 + j;
    v = cv[CV_R3 + l*4096 + k*64 + nt*16 + n];
  }
  swz[i] = f2bs(v);
}

// ---------------- CSR build ----------------
__global__ void k_hist(const int* __restrict__ dst, int* __restrict__ deg){
  int e = blockIdx.x * 256 + threadIdx.x;
  if (e < N_EDGES) atomicAdd(&deg[dst[e]], 1);
}

__global__ void k_scan(const int* __restrict__ deg, int* __restrict__ row_start,
                       int* __restrict__ cursor){
  __shared__ int lds[1024];
  int t = threadIdx.x;
  int v[8]; int tot = 0;
#pragma unroll
  for (int k = 0; k < 8; k++){ v[k] = deg[t*8+k]; tot += v[k]; }
  lds[t] = tot; __syncthreads();
  for (int off = 1; off < 1024; off <<= 1){
    int x = (t >= off) ? lds[t-off] : 0;
    __syncthreads();
    lds[t] += x;
    __syncthreads();
  }
  int base = lds[t] - tot;
#pragma unroll
  for (int k = 0; k < 8; k++){ row_start[t*8+k] = base; cursor[t*8+k] = base; base += v[k]; }
  if (t == 1023) row_start[N_NODES] = base;
}

// fill: slot -> src node and slot -> dst node
__global__ void k_fill(const int* __restrict__ ei, int* __restrict__ cursor,
                       int* __restrict__ sslot, int* __restrict__ dslot){
  int e = blockIdx.x * 256 + threadIdx.x;
  if (e < N_EDGES){
    int d = ei[N_EDGES + e];
    int slot = atomicAdd(&cursor[d], 1);
    sslot[slot] = ei[e];
    dslot[slot] = d;
  }
}

// ------- edge geometry in SLOT order: Y[slot][16], r[slot] (coalesced writes) -----
__global__ void k_geom(const float* __restrict__ posf, const int* __restrict__ sslot,
                       const int* __restrict__ dslot, float* __restrict__ Y,
                       float* __restrict__ rbuf){
  int t = blockIdx.x * 256 + threadIdx.x;
  if (t >= N_EDGES) return;
  int s = sslot[t], d = dslot[t];
  float vx = posf[d*3+0] - posf[s*3+0];
  float vy = posf[d*3+1] - posf[s*3+1];
  float vz = posf[d*3+2] - posf[s*3+2];
  float r = sqrtf(vx*vx + vy*vy + vz*vz + 1e-12f);
  float ir = 1.0f / r;
  float x = vx*ir, y = vy*ir, z = vz*ir;
  const float s3 = 1.7320508075688772f, s15 = 3.872983346207417f, s5 = 2.23606797749979f;
  const float s105 = 10.246950765959598f, s7 = 2.6457513110645907f;
  const float c35 = 2.091650066335189f, c21 = 1.6201851746019651f;
  float x2 = x*x, y2 = y*y, z2 = z*z;
  float4* Yp = (float4*)(Y + (size_t)t*16);
  Yp[0] = make_float4(1.0f, s3*x, s3*y, s3*z);
  Yp[1] = make_float4(s15*x*y, s15*y*z, 0.5f*s5*(3.0f*z2-1.0f), s15*x*z);
  Yp[2] = make_float4(0.5f*s15*(x2-y2), c35*y*(3.0f*x2-y2), s105*x*y*z, c21*y*(5.0f*z2-1.0f));
  Yp[3] = make_float4(0.5f*s7*(5.0f*z2*z-3.0f*z), c21*x*(5.0f*z2-1.0f),
                      0.5f*s105*z*(x2-y2), c35*x*(x2-3.0f*y2));
  rbuf[t] = r;
}

// ---------------- h init ----------------
__global__ void k_hinit(const int* __restrict__ types, const float* __restrict__ Wemb,
                        float* __restrict__ h){
  int i = blockIdx.x * 256 + threadIdx.x;
  if (i >= N_NODES * 64) return;
  int n = i >> 6, c = i & 63;
  h[i] = Wemb[types[n]*64 + c];
}

// -------- MFMA radial MLP (8->64->64->64), fused h[src] multiply -> G[slot,c] -----
#define ROWS 72
__global__ void __launch_bounds__(256) k_mlp(const float* __restrict__ rbuf,
        const short* __restrict__ sw, const float* __restrict__ h_old,
        const int* __restrict__ sslot, bf16* __restrict__ Gb){
  __shared__ short lds[4][16*ROWS];
  int tix = threadIdx.x;
  int wv = tix >> 6, lane = tix & 63;
  int q = lane >> 4, nn = lane & 15;
  int ebase = blockIdx.x*64 + wv*16;

  float r = rbuf[ebase + nn];
  float xc = r * 0.2f;
  float f = 0.0f;
  if (xc < 1.0f){
    float x3 = xc*xc*xc, x6 = x3*x3, x7 = x6*xc, x8 = x7*xc;
    f = 1.0f - 28.0f*x6 + 48.0f*x7 - 21.0f*x8;
  }
  float bs = 0.6324555320336759f * f / r;
  float t0 = PI_F * r * 0.2f;
  float ef[8];
#pragma unroll
  for (int k = 0; k < 8; k++) ef[k] = bs * __sinf((float)(k+1) * t0);

  bf16x8 af1 = {0,0,0,0,0,0,0,0};
  if (q == 0){
#pragma unroll
    for (int j = 0; j < 8; j++) af1[j] = f2bs(ef[j]);
  }

  const bf16x8* S1 = (const bf16x8*)(sw);
  const bf16x8* S2 = (const bf16x8*)(sw + 2048);
  const bf16x8* S3 = (const bf16x8*)(sw + 6144);
  short* A = lds[wv];

  f32x4 acc[4];
#pragma unroll
  for (int t = 0; t < 4; t++){
    bf16x8 b = S1[t*64 + q*16 + nn];
    f32x4 z = {0.f,0.f,0.f,0.f};
    acc[t] = __builtin_amdgcn_mfma_f32_16x16x32_bf16(af1, b, z, 0, 0, 0);
  }
#pragma unroll
  for (int t = 0; t < 4; t++)
#pragma unroll
    for (int rg = 0; rg < 4; rg++)
      A[(q*4+rg)*ROWS + t*16 + nn] = f2bs(silu_f(acc[t][rg]));
  __syncthreads();

  bf16x8 a0 = *(const bf16x8*)&A[nn*ROWS + 0*32 + q*8];
  bf16x8 a1 = *(const bf16x8*)&A[nn*ROWS + 1*32 + q*8];
  __syncthreads();
#pragma unroll
  for (int t = 0; t < 4; t++){
    f32x4 z = {0.f,0.f,0.f,0.f};
    bf16x8 b0 = S2[t*128 + 0*64 + q*16 + nn];
    bf16x8 b1 = S2[t*128 + 1*64 + q*16 + nn];
    z = __builtin_amdgcn_mfma_f32_16x16x32_bf16(a0, b0, z, 0, 0, 0);
    z = __builtin_amdgcn_mfma_f32_16x16x32_bf16(a1, b1, z, 0, 0, 0);
    acc[t] = z;
  }
#pragma unroll
  for (int t = 0; t < 4; t++)
#pragma unroll
    for (int rg = 0; rg < 4; rg++)
      A[(q*4+rg)*ROWS + t*16 + nn] = f2bs(silu_f(acc[t][rg]));
  __syncthreads();

  a0 = *(const bf16x8*)&A[nn*ROWS + 0*32 + q*8];
  a1 = *(const bf16x8*)&A[nn*ROWS + 1*32 + q*8];
  __syncthreads();
#pragma unroll
  for (int t = 0; t < 4; t++){
    f32x4 z = {0.f,0.f,0.f,0.f};
    bf16x8 b0 = S3[t*128 + 0*64 + q*16 + nn];
    bf16x8 b1 = S3[t*128 + 1*64 + q*16 + nn];
    z = __builtin_amdgcn_mfma_f32_16x16x32_bf16(a0, b0, z, 0, 0, 0);
    z = __builtin_amdgcn_mfma_f32_16x16x32_bf16(a1, b1, z, 0, 0, 0);
    acc[t] = z;
  }
#pragma unroll
  for (int t = 0; t < 4; t++)
#pragma unroll
    for (int rg = 0; rg < 4; rg++)
      A[(q*4+rg)*ROWS + t*16 + nn] = f2bs(acc[t][rg]);
  __syncthreads();

  // G = bf16(Rw * h_old[src]) ; lane covers 16 channels [c4*16, c4*16+16) of slot row
  int row = lane >> 2, c4 = lane & 3;
  int src = sslot[ebase + row];
  const float4* hp = (const float4*)(h_old + (size_t)src*64 + c4*16);
  float4 h0 = hp[0], h1 = hp[1], h2 = hp[2], h3 = hp[3];
  float hval[16] = {h0.x,h0.y,h0.z,h0.w, h1.x,h1.y,h1.z,h1.w,
                    h2.x,h2.y,h2.z,h2.w, h3.x,h3.y,h3.z,h3.w};
  union { uint4 u[2]; unsigned short s[16]; } rw;
  rw.u[0] = *(const uint4*)&A[row*ROWS + c4*16];
  rw.u[1] = *(const uint4*)&A[row*ROWS + c4*16 + 8];
  union { bf16 b[16]; uint4 u[2]; } g;
#pragma unroll
  for (int kk = 0; kk < 16; kk++)
    g.b[kk] = __float2bfloat16(bfbits2f(rw.s[kk]) * hval[kk]);
  uint4* gp = (uint4*)(Gb + ((size_t)(ebase + row))*64 + c4*16);
  gp[0] = g.u[0];
  gp[1] = g.u[1];
}

// ------- node update + readout: wave per node, lane = channel; ZERO indirection ---
template<int LAYER_KIND>
__global__ void __launch_bounds__(256) k_gu(const bf16* __restrict__ Gb,
        const float* __restrict__ h_old, float* __restrict__ h_new,
        const float* __restrict__ Y, const int* __restrict__ row_start,
        const int* __restrict__ types, const float* __restrict__ WscT,
        const float* __restrict__ wprod, const float* __restrict__ wro0,
        const float* __restrict__ Wro1a, const float* __restrict__ wro1b,
        const int* __restrict__ batch, float* __restrict__ ene){
  __shared__ float hn_l[4][64];
  int tix = threadIdx.x;
  int wv = tix >> 6, lane = tix & 63;
  int n = __builtin_amdgcn_readfirstlane((blockIdx.x * 256 + tix) >> 6);
  int beg = row_start[n], end = row_start[n+1];
  const unsigned short* G = (const unsigned short*)Gb;
  float acc[16];
#pragma unroll
  for (int s = 0; s < 16; s++) acc[s] = 0.0f;
  for (int it = beg; it < end; it += 4){
    int last = end - 1;
    int i1 = min(it+1, last), i2 = min(it+2, last), i3 = min(it+3, last);
    float g0 = bfbits2f(G[(size_t)it*64 + lane]);
    float g1 = bfbits2f(G[(size_t)i1*64 + lane]);
    float g2 = bfbits2f(G[(size_t)i2*64 + lane]);
    float g3 = bfbits2f(G[(size_t)i3*64 + lane]);
    if (it+1 >= end) g1 = 0.0f;
    if (it+2 >= end) g2 = 0.0f;
    if (it+3 >= end) g3 = 0.0f;
    const float4* yp0 = (const float4*)(Y + (size_t)it*16);
    const float4* yp1 = (const float4*)(Y + (size_t)i1*16);
    const float4* yp2 = (const float4*)(Y + (size_t)i2*16);
    const float4* yp3 = (const float4*)(Y + (size_t)i3*16);
    float4 a0 = yp0[0], a1 = yp0[1], a2 = yp0[2], a3 = yp0[3];
    float4 b0 = yp1[0], b1 = yp1[1], b2 = yp1[2], b3 = yp1[3];
    float4 c0 = yp2[0], c1 = yp2[1], c2 = yp2[2], c3 = yp2[3];
    float4 d0 = yp3[0], d1 = yp3[1], d2 = yp3[2], d3 = yp3[3];
    acc[0]  += g0*a0.x + g1*b0.x + g2*c0.x + g3*d0.x;
    acc[1]  += g0*a0.y + g1*b0.y + g2*c0.y + g3*d0.y;
    acc[2]  += g0*a0.z + g1*b0.z + g2*c0.z + g3*d0.z;
    acc[3]  += g0*a0.w + g1*b0.w + g2*c0.w + g3*d0.w;
    acc[4]  += g0*a1.x + g1*b1.x + g2*c1.x + g3*d1.x;
    acc[5]  += g0*a1.y + g1*b1.y + g2*c1.y + g3*d1.y;
    acc[6]  += g0*a1.z + g1*b1.z + g2*c1.z + g3*d1.z;
    acc[7]  += g0*a1.w + g1*b1.w + g2*c1.w + g3*d1.w;
    acc[8]  += g0*a2.x + g1*b2.x + g2*c2.x + g3*d2.x;
    acc[9]  += g0*a2.y + g1*b2.y + g2*c2.y + g3*d2.y;
    acc[10] += g0*a2.z + g1*b2.z + g2*c2.z + g3*d2.z;
    acc[11] += g0*a2.w + g1*b2.w + g2*c2.w + g3*d2.w;
    acc[12] += g0*a3.x + g1*b3.x + g2*c3.x + g3*d3.x;
    acc[13] += g0*a3.y + g1*b3.y + g2*c3.y + g3*d3.y;
    acc[14] += g0*a3.z + g1*b3.z + g2*c3.z + g3*d3.z;
    acc[15] += g0*a3.w + g1*b3.w + g2*c3.w + g3*d3.w;
  }
#pragma unroll
  for (int s = 0; s < 16; s++) acc[s] *= INV_AVG;

  int ty = __builtin_amdgcn_readfirstlane(types[n]);
  // transposed Wsc: lane d reads its contiguous 64-float row; h row is wave-uniform
  const float4* wt = (const float4*)(WscT + (size_t)ty*4096 + lane*64);
  const float4* hr = (const float4*)(h_old + (size_t)n*64);
  float sc = 0.0f;
#pragma unroll
  for (int cq = 0; cq < 16; cq++){
    float4 wv4 = wt[cq];
    float4 hv4 = hr[cq];
    sc += wv4.x*hv4.x + wv4.y*hv4.y + wv4.z*hv4.z + wv4.w*hv4.w;
  }

  float inv0 = acc[0];
  float inv1 = acc[1]*acc[1] + acc[2]*acc[2] + acc[3]*acc[3];
  float inv2 = acc[4]*acc[4] + acc[5]*acc[5] + acc[6]*acc[6] + acc[7]*acc[7]
             + acc[8]*acc[8];
  float inv3 = acc[9]*acc[9] + acc[10]*acc[10] + acc[11]*acc[11] + acc[12]*acc[12]
             + acc[13]*acc[13] + acc[14]*acc[14] + acc[15]*acc[15];
  const float* wp = wprod + ty*4;
  float hn = inv0*wp[0] + inv1*wp[1] + inv2*wp[2] + inv3*wp[3] + sc;
  h_new[(size_t)n*64 + lane] = hn;

  float ev;
  if (LAYER_KIND == 0){
    float p = hn * wro0[lane];
#pragma unroll
    for (int off = 32; off >= 1; off >>= 1) p += __shfl_xor(p, off, 64);
    ev = p;
  } else {
    // LDS transpose: lane j computes p_j = sum_c hn[c]*W[c][j] (quads redundant)
    hn_l[wv][lane] = hn;
    int j = lane & 15;
    float pj = 0.0f;
#pragma unroll
    for (int c = 0; c < 64; c++)
      pj += hn_l[wv][c] * Wro1a[c*16 + j];
    float evj = silu_f(pj) * wro1b[j];
    evj += __shfl_xor(evj, 8, 64);
    evj += __shfl_xor(evj, 4, 64);
    evj += __shfl_xor(evj, 2, 64);
    evj += __shfl_xor(evj, 1, 64);
    ev = evj;
  }
  if (lane == 0) atomicAdd(&ene[batch[n]], ev);
}

// ---------------- final output convert (format matches detected input) ----------
__global__ void k_out(const float* __restrict__ ene, const int* __restrict__ flag,
                      void* __restrict__ out){
  int t = threadIdx.x;
  if (t < NGRP){
    if (*flag) ((bf16*)out)[t] = __float2bfloat16(ene[t]);
    else       ((float*)out)[t] = ene[t];
  }
}

static inline size_t rup(size_t x){ return (x + 255) & ~(size_t)255; }

extern "C" void kernel_launch(void* const* d_in, const int* in_sizes, int n_in,
                              void* d_out, int out_size, void* d_ws, size_t ws_size,
                              hipStream_t stream) {
  const void* pos   = d_in[0];
  const int*  types = (const int*)d_in[1];
  const int*  ei    = (const int*)d_in[2];
  const int*  batch = (const int*)d_in[3];
  const void* Wemb  = d_in[4];
  const void* Wr1   = d_in[5];
  const void* Wr2   = d_in[6];
  const void* Wr3   = d_in[7];
  const void* Wsc   = d_in[8];
  const void* wprod = d_in[9];
  const void* wro0  = d_in[10];
  const void* Wro1a = d_in[11];
  const void* wro1b = d_in[12];

  char* w = (char*)d_ws;
  int*   flag     = (int*)  w; w += 256;
  float* cv       = (float*)w; w += rup((size_t)CVT_N*4);
  short* swz      = (short*)w; w += rup((size_t)SWZ_N*2);
  float* ene      = (float*)w; w += 256;
  int*   deg      = (int*)  w; w += rup((size_t)N_NODES*4);
  int*   row_start= (int*)  w; w += rup((size_t)(N_NODES+1)*4);
  int*   cursor   = (int*)  w; w += rup((size_t)N_NODES*4);
  int*   sslot    = (int*)  w; w += rup((size_t)N_EDGES*4);
  int*   dslot    = (int*)  w; w += rup((size_t)N_EDGES*4);
  float* h0       = (float*)w; w += rup((size_t)N_NODES*64*4);
  float* h1       = (float*)w; w += rup((size_t)N_NODES*64*4);
  float* rbuf     = (float*)w; w += rup((size_t)N_EDGES*4);
  float* Y        = (float*)w; w += rup((size_t)N_EDGES*16*4);
  bf16*  Gb       = (bf16*) w; w += rup((size_t)N_EDGES*64*2);

  hipMemsetAsync(deg, 0, N_NODES*4, stream);
  hipMemsetAsync(ene, 0, NGRP*4, stream);

  const int* dstp = ei + N_EDGES;
  k_detect<<<1, 64, 0, stream>>>(pos, flag);
  k_cvt<<<(CVT_N + 255)/256, 256, 0, stream>>>(pos, Wemb, Wr1, Wr2, Wr3, Wsc,
                                               wprod, wro0, Wro1a, wro1b, flag, cv);
  k_swz<<<SWZ_N/256, 256, 0, stream>>>(cv, swz);
  k_hist<<<N_EDGES/256, 256, 0, stream>>>(dstp, deg);
  k_scan<<<1, 1024, 0, stream>>>(deg, row_start, cursor);
  k_fill<<<N_EDGES/256, 256, 0, stream>>>(ei, cursor, sslot, dslot);
  k_geom<<<N_EDGES/256, 256, 0, stream>>>(cv + CV_POS, sslot, dslot, Y, rbuf);
  k_hinit<<<(N_NODES*64)/256, 256, 0, stream>>>(types, cv + CV_EMB, h0);

  float* hc = h0; float* hx = h1;
  for (int i = 0; i < NLAY; i++){
    k_mlp<<<N_EDGES/64, 256, 0, stream>>>(rbuf, swz + i*SWZ_PER_L, hc, sslot, Gb);
    if (i == 0)
      k_gu<0><<<(N_NODES*64)/256, 256, 0, stream>>>(Gb, hc, hx, Y,
          row_start, types, cv + CV_SC + (size_t)i*NELM*4096, cv + CV_PROD + i*NELM*4,
          cv + CV_RO0, cv + CV_RO1A, cv + CV_RO1B, batch, ene);
    else
      k_gu<1><<<(N_NODES*64)/256, 256, 0, stream>>>(Gb, hc, hx, Y,
          row_start, types, cv + CV_SC + (size_t)i*NELM*4096, cv + CV_PROD + i*NELM*4,
          cv + CV_RO0, cv + CV_RO1A, cv + CV_RO1B, batch, ene);
    float* tmp = hc; hc = hx; hx = tmp;
  }
  k_out<<<1, 64, 0, stream>>>(ene, flag, d_out);
}

// Round 8
// 225.658 us; speedup vs baseline: 1.7075x; 1.7075x over previous
//
#include <hip/hip_runtime.h>
#include <hip/hip_bf16.h>
#include <math.h>

#define N_NODES 8192
#define N_EDGES 131072
#define NGRP 16
#define NLAY 2
#define NELM 4
constexpr float INV_AVG = 1.0f / 16.0f;
constexpr float PI_F = 3.14159265358979323846f;

// converted fp32 buffer layout (element offsets)
#define CV_POS   0        // 24576
#define CV_EMB   24576    // 256
#define CV_R1    24832    // 1024  (natural [l][k:8][n:64])
#define CV_R2    25856    // 8192  (natural [l][k:64][n:64])
#define CV_R3    34048    // 8192  (natural [l][k:64][n:64])
#define CV_SC    42240    // 32768 (natural [l][ty][c:64][d:64])
#define CV_PROD  75008    // 32
#define CV_RO0   75040    // 64
#define CV_RO1A  75104    // 1024
#define CV_RO1B  76128    // 16
#define CVT_N    76144

// swizzled bf16 MFMA B-fragment weight buffer: per layer 10240 shorts
#define SWZ_PER_L 10240
#define SWZ_N     20480

typedef __hip_bfloat16 bf16;
typedef __attribute__((ext_vector_type(8))) short bf16x8;
typedef __attribute__((ext_vector_type(4))) float f32x4;

__device__ __forceinline__ float silu_f(float x){ return x / (1.0f + __expf(-x)); }
__device__ __forceinline__ float bfbits2f(unsigned short u){
  return __uint_as_float(((unsigned)u) << 16);
}
__device__ __forceinline__ void unpack2(unsigned u, float& lo, float& hi){
  lo = __uint_as_float(u << 16);
  hi = __uint_as_float(u & 0xffff0000u);
}
__device__ __forceinline__ short f2bs(float v){
  union { bf16 b; short s; } u; u.b = __float2bfloat16(v); return u.s;
}
// dtype-agnostic element load: flag==1 -> buffer is bf16, else fp32
__device__ __forceinline__ float ldf(const void* p, int i, int flag){
  if (flag) return bfbits2f(((const unsigned short*)p)[i]);
  return ((const float*)p)[i];
}

// ---------------- input dtype detection (1 wave) ----------------
__global__ void k_detect(const void* __restrict__ pos, int* __restrict__ flag){
  int t = threadIdx.x;  // 64 lanes
  const unsigned short* u = (const unsigned short*)pos;
  float va = bfbits2f(u[2*t]), vb = bfbits2f(u[2*t+1]);
  bool bad = !(fabsf(va) <= 1000.0f) || !(fabsf(vb) <= 1000.0f);
  unsigned long long m = __ballot(bad);
  if (t == 0) *flag = (m != 0ull) ? 0 : 1;
}

// ---------------- convert all float inputs to fp32 ws copies ----------------
__global__ void k_cvt(const void* __restrict__ pos, const void* __restrict__ Wemb,
                      const void* __restrict__ Wr1, const void* __restrict__ Wr2,
                      const void* __restrict__ Wr3, const void* __restrict__ Wsc,
                      const void* __restrict__ wprod, const void* __restrict__ wro0,
                      const void* __restrict__ Wro1a, const void* __restrict__ wro1b,
                      const int* __restrict__ flag, float* __restrict__ cv){
  int i = blockIdx.x * 256 + threadIdx.x;
  int fl = *flag;
  if (i < 24576){ cv[CV_POS + i] = ldf(pos, i, fl); return; }
  if (i < 24832){ int j = i - 24576; cv[CV_EMB + j] = ldf(Wemb, j, fl); return; }
  if (i < 25856){ int j = i - 24832; cv[CV_R1  + j] = ldf(Wr1,  j, fl); return; }
  if (i < 34048){ int j = i - 25856; cv[CV_R2  + j] = ldf(Wr2,  j, fl); return; }
  if (i < 42240){ int j = i - 34048; cv[CV_R3  + j] = ldf(Wr3,  j, fl); return; }
  if (i < 75008){ int j = i - 42240; cv[CV_SC  + j] = ldf(Wsc,  j, fl); return; }
  if (i < 75040){ int j = i - 75008; cv[CV_PROD+ j] = ldf(wprod,j, fl); return; }
  if (i < 75104){ int j = i - 75040; cv[CV_RO0 + j] = ldf(wro0, j, fl); return; }
  if (i < 76128){ int j = i - 75104; cv[CV_RO1A+ j] = ldf(Wro1a,j, fl); return; }
  if (i < CVT_N){ int j = i - 76128; cv[CV_RO1B+ j] = ldf(wro1b,j, fl); return; }
}

// ---------------- build MFMA B-fragment-order bf16 weights ----------------
__global__ void k_swz(const float* __restrict__ cv, short* __restrict__ swz){
  int i = blockIdx.x * 256 + threadIdx.x;   // 20480 exact
  int l = i / SWZ_PER_L, w = i % SWZ_PER_L;
  float v;
  if (w < 2048){
    int t = w >> 9, q = (w >> 7) & 3, n = (w >> 3) & 15, j = w & 7;
    int k = q*8 + j;
    v = (k < 8) ? cv[CV_R1 + l*512 + k*64 + t*16 + n] : 0.0f;
  } else if (w < 6144){
    int w2 = w - 2048;
    int nt = w2 >> 10, kt = (w2 >> 9) & 1, q = (w2 >> 7) & 3, n = (w2 >> 3) & 15, j = w2 & 7;
    int k = kt*32 + q*8 + j;
    v = cv[CV_R2 + l*4096 + k*64 + nt*16 + n];
  } else {
    int w3 = w - 6144;
    int nt = w3 >> 10, kt = (w3 >> 9) & 1, q = (w3 >> 7) & 3, n = (w3 >> 3) & 15, j = w3 & 7;
    int k = kt*32 + q*8 + j;
    v = cv[CV_R3 + l*4096 + k*64 + nt*16 + n];
  }
  swz[i] = f2bs(v);
}

// ---------------- CSR build ----------------
__global__ void k_hist(const int* __restrict__ dst, int* __restrict__ deg){
  int e = blockIdx.x * 256 + threadIdx.x;
  if (e < N_EDGES) atomicAdd(&deg[dst[e]], 1);
}

__global__ void k_scan(const int* __restrict__ deg, int* __restrict__ row_start,
                       int* __restrict__ cursor){
  __shared__ int lds[1024];
  int t = threadIdx.x;
  int v[8]; int tot = 0;
#pragma unroll
  for (int k = 0; k < 8; k++){ v[k] = deg[t*8+k]; tot += v[k]; }
  lds[t] = tot; __syncthreads();
  for (int off = 1; off < 1024; off <<= 1){
    int x = (t >= off) ? lds[t-off] : 0;
    __syncthreads();
    lds[t] += x;
    __syncthreads();
  }
  int base = lds[t] - tot;
#pragma unroll
  for (int k = 0; k < 8; k++){ row_start[t*8+k] = base; cursor[t*8+k] = base; base += v[k]; }
  if (t == 1023) row_start[N_NODES] = base;
}

// fill: slot -> src node and slot -> dst node
__global__ void k_fill(const int* __restrict__ ei, int* __restrict__ cursor,
                       int* __restrict__ sslot, int* __restrict__ dslot){
  int e = blockIdx.x * 256 + threadIdx.x;
  if (e < N_EDGES){
    int d = ei[N_EDGES + e];
    int slot = atomicAdd(&cursor[d], 1);
    sslot[slot] = ei[e];
    dslot[slot] = d;
  }
}

// ------- edge geometry in SLOT order: Yb[slot][16] bf16 + r[slot] ----------------
__global__ void k_geom(const float* __restrict__ posf, const int* __restrict__ sslot,
                       const int* __restrict__ dslot, unsigned short* __restrict__ Yb,
                       float* __restrict__ rbuf){
  int t = blockIdx.x * 256 + threadIdx.x;
  if (t >= N_EDGES) return;
  int s = sslot[t], d = dslot[t];
  float vx = posf[d*3+0] - posf[s*3+0];
  float vy = posf[d*3+1] - posf[s*3+1];
  float vz = posf[d*3+2] - posf[s*3+2];
  float r = sqrtf(vx*vx + vy*vy + vz*vz + 1e-12f);
  float ir = 1.0f / r;
  float x = vx*ir, y = vy*ir, z = vz*ir;
  const float s3 = 1.7320508075688772f, s15 = 3.872983346207417f, s5 = 2.23606797749979f;
  const float s105 = 10.246950765959598f, s7 = 2.6457513110645907f;
  const float c35 = 2.091650066335189f, c21 = 1.6201851746019651f;
  float x2 = x*x, y2 = y*y, z2 = z*z;
  float ys[16] = {
    1.0f, s3*x, s3*y, s3*z,
    s15*x*y, s15*y*z, 0.5f*s5*(3.0f*z2-1.0f), s15*x*z,
    0.5f*s15*(x2-y2), c35*y*(3.0f*x2-y2), s105*x*y*z, c21*y*(5.0f*z2-1.0f),
    0.5f*s7*(5.0f*z2*z-3.0f*z), c21*x*(5.0f*z2-1.0f), 0.5f*s105*z*(x2-y2),
    c35*x*(x2-3.0f*y2) };
  union { bf16 b[16]; uint4 u[2]; } pk;
#pragma unroll
  for (int k = 0; k < 16; k++) pk.b[k] = __float2bfloat16(ys[k]);
  uint4* yp = (uint4*)(Yb + (size_t)t*16);
  yp[0] = pk.u[0];
  yp[1] = pk.u[1];
  rbuf[t] = r;
}

// ---------------- h init ----------------
__global__ void k_hinit(const int* __restrict__ types, const float* __restrict__ Wemb,
                        float* __restrict__ h){
  int i = blockIdx.x * 256 + threadIdx.x;
  if (i >= N_NODES * 64) return;
  int n = i >> 6, c = i & 63;
  h[i] = Wemb[types[n]*64 + c];
}

// -------- MFMA radial MLP (8->64->64->64), fused h[src] multiply -> G[slot,c] -----
#define ROWS 72
__global__ void __launch_bounds__(256) k_mlp(const float* __restrict__ rbuf,
        const short* __restrict__ sw, const float* __restrict__ h_old,
        const int* __restrict__ sslot, bf16* __restrict__ Gb){
  __shared__ short lds[4][16*ROWS];
  int tix = threadIdx.x;
  int wv = tix >> 6, lane = tix & 63;
  int q = lane >> 4, nn = lane & 15;
  int ebase = blockIdx.x*64 + wv*16;

  float r = rbuf[ebase + nn];
  float xc = r * 0.2f;
  float f = 0.0f;
  if (xc < 1.0f){
    float x3 = xc*xc*xc, x6 = x3*x3, x7 = x6*xc, x8 = x7*xc;
    f = 1.0f - 28.0f*x6 + 48.0f*x7 - 21.0f*x8;
  }
  float bs = 0.6324555320336759f * f / r;
  float t0 = PI_F * r * 0.2f;
  float ef[8];
#pragma unroll
  for (int k = 0; k < 8; k++) ef[k] = bs * __sinf((float)(k+1) * t0);

  bf16x8 af1 = {0,0,0,0,0,0,0,0};
  if (q == 0){
#pragma unroll
    for (int j = 0; j < 8; j++) af1[j] = f2bs(ef[j]);
  }

  const bf16x8* S1 = (const bf16x8*)(sw);
  const bf16x8* S2 = (const bf16x8*)(sw + 2048);
  const bf16x8* S3 = (const bf16x8*)(sw + 6144);
  short* A = lds[wv];

  f32x4 acc[4];
#pragma unroll
  for (int t = 0; t < 4; t++){
    bf16x8 b = S1[t*64 + q*16 + nn];
    f32x4 z = {0.f,0.f,0.f,0.f};
    acc[t] = __builtin_amdgcn_mfma_f32_16x16x32_bf16(af1, b, z, 0, 0, 0);
  }
#pragma unroll
  for (int t = 0; t < 4; t++)
#pragma unroll
    for (int rg = 0; rg < 4; rg++)
      A[(q*4+rg)*ROWS + t*16 + nn] = f2bs(silu_f(acc[t][rg]));
  __syncthreads();

  bf16x8 a0 = *(const bf16x8*)&A[nn*ROWS + 0*32 + q*8];
  bf16x8 a1 = *(const bf16x8*)&A[nn*ROWS + 1*32 + q*8];
  __syncthreads();
#pragma unroll
  for (int t = 0; t < 4; t++){
    f32x4 z = {0.f,0.f,0.f,0.f};
    bf16x8 b0 = S2[t*128 + 0*64 + q*16 + nn];
    bf16x8 b1 = S2[t*128 + 1*64 + q*16 + nn];
    z = __builtin_amdgcn_mfma_f32_16x16x32_bf16(a0, b0, z, 0, 0, 0);
    z = __builtin_amdgcn_mfma_f32_16x16x32_bf16(a1, b1, z, 0, 0, 0);
    acc[t] = z;
  }
#pragma unroll
  for (int t = 0; t < 4; t++)
#pragma unroll
    for (int rg = 0; rg < 4; rg++)
      A[(q*4+rg)*ROWS + t*16 + nn] = f2bs(silu_f(acc[t][rg]));
  __syncthreads();

  a0 = *(const bf16x8*)&A[nn*ROWS + 0*32 + q*8];
  a1 = *(const bf16x8*)&A[nn*ROWS + 1*32 + q*8];
  __syncthreads();
#pragma unroll
  for (int t = 0; t < 4; t++){
    f32x4 z = {0.f,0.f,0.f,0.f};
    bf16x8 b0 = S3[t*128 + 0*64 + q*16 + nn];
    bf16x8 b1 = S3[t*128 + 1*64 + q*16 + nn];
    z = __builtin_amdgcn_mfma_f32_16x16x32_bf16(a0, b0, z, 0, 0, 0);
    z = __builtin_amdgcn_mfma_f32_16x16x32_bf16(a1, b1, z, 0, 0, 0);
    acc[t] = z;
  }
#pragma unroll
  for (int t = 0; t < 4; t++)
#pragma unroll
    for (int rg = 0; rg < 4; rg++)
      A[(q*4+rg)*ROWS + t*16 + nn] = f2bs(acc[t][rg]);
  __syncthreads();

  // G = bf16(Rw * h_old[src]) ; lane covers 16 channels of one slot row
  int row = lane >> 2, c4 = lane & 3;
  int src = sslot[ebase + row];
  const float4* hp = (const float4*)(h_old + (size_t)src*64 + c4*16);
  float4 h0 = hp[0], h1 = hp[1], h2 = hp[2], h3 = hp[3];
  float hval[16] = {h0.x,h0.y,h0.z,h0.w, h1.x,h1.y,h1.z,h1.w,
                    h2.x,h2.y,h2.z,h2.w, h3.x,h3.y,h3.z,h3.w};
  union { uint4 u[2]; unsigned short s[16]; } rw;
  rw.u[0] = *(const uint4*)&A[row*ROWS + c4*16];
  rw.u[1] = *(const uint4*)&A[row*ROWS + c4*16 + 8];
  union { bf16 b[16]; uint4 u[2]; } g;
#pragma unroll
  for (int kk = 0; kk < 16; kk++)
    g.b[kk] = __float2bfloat16(bfbits2f(rw.s[kk]) * hval[kk]);
  uint4* gp = (uint4*)(Gb + ((size_t)(ebase + row))*64 + c4*16);
  gp[0] = g.u[0];
  gp[1] = g.u[1];
}

// ------- node update + readout: wave per node, lane = channel ---------------------
// Sequential G/Yb streams, 8-edge groups with explicit load->compute phases.
#define UNR 8
template<int LAYER_KIND>
__global__ void __launch_bounds__(256, 4) k_gu(const bf16* __restrict__ Gb,
        const float* __restrict__ h_old, float* __restrict__ h_new,
        const unsigned short* __restrict__ Yb, const int* __restrict__ row_start,
        const int* __restrict__ types, const float* __restrict__ Wsc,
        const float* __restrict__ wprod, const float* __restrict__ wro0,
        const float* __restrict__ Wro1a, const float* __restrict__ wro1b,
        const int* __restrict__ batch, float* __restrict__ ene){
  __shared__ float ebins[NGRP];
  __shared__ float hn_l[4][64];
  int tix = threadIdx.x;
  if (tix < NGRP) ebins[tix] = 0.0f;
  __syncthreads();
  int wv = tix >> 6, lane = tix & 63;
  int n = __builtin_amdgcn_readfirstlane((blockIdx.x * 256 + tix) >> 6);
  {
    int beg = row_start[n], end = row_start[n+1];
    const unsigned short* G = (const unsigned short*)Gb;
    float acc[16];
#pragma unroll
    for (int s = 0; s < 16; s++) acc[s] = 0.0f;
    int last = end - 1;
    for (int it = beg; it < end; it += UNR){
      // ---- load phase: all independent ----
      float gv[UNR];
      uint4 ya[UNR], yc[UNR];
#pragma unroll
      for (int k = 0; k < UNR; k++){
        int ic = min(it + k, last);
        gv[k] = bfbits2f(G[(size_t)ic*64 + lane]);
        const uint4* yp = (const uint4*)(Yb + (size_t)ic*16);
        ya[k] = yp[0];
        yc[k] = yp[1];
      }
      // ---- compute phase ----
#pragma unroll
      for (int k = 0; k < UNR; k++){
        float g = (it + k < end) ? gv[k] : 0.0f;
        float lo, hi;
        unpack2(ya[k].x, lo, hi); acc[0]  += g*lo; acc[1]  += g*hi;
        unpack2(ya[k].y, lo, hi); acc[2]  += g*lo; acc[3]  += g*hi;
        unpack2(ya[k].z, lo, hi); acc[4]  += g*lo; acc[5]  += g*hi;
        unpack2(ya[k].w, lo, hi); acc[6]  += g*lo; acc[7]  += g*hi;
        unpack2(yc[k].x, lo, hi); acc[8]  += g*lo; acc[9]  += g*hi;
        unpack2(yc[k].y, lo, hi); acc[10] += g*lo; acc[11] += g*hi;
        unpack2(yc[k].z, lo, hi); acc[12] += g*lo; acc[13] += g*hi;
        unpack2(yc[k].w, lo, hi); acc[14] += g*lo; acc[15] += g*hi;
      }
    }
#pragma unroll
    for (int s = 0; s < 16; s++) acc[s] *= INV_AVG;

    int ty = __builtin_amdgcn_readfirstlane(types[n]);
    const float* Ws = Wsc + (size_t)ty*4096;
    float sc = 0.0f;
#pragma unroll 8
    for (int c = 0; c < 64; c++)
      sc += h_old[(size_t)n*64 + c] * Ws[c*64 + lane];  // h term wave-uniform -> s_load

    float inv0 = acc[0];
    float inv1 = acc[1]*acc[1] + acc[2]*acc[2] + acc[3]*acc[3];
    float inv2 = acc[4]*acc[4] + acc[5]*acc[5] + acc[6]*acc[6] + acc[7]*acc[7]
               + acc[8]*acc[8];
    float inv3 = acc[9]*acc[9] + acc[10]*acc[10] + acc[11]*acc[11] + acc[12]*acc[12]
               + acc[13]*acc[13] + acc[14]*acc[14] + acc[15]*acc[15];
    const float* wp = wprod + ty*4;
    float hn = inv0*wp[0] + inv1*wp[1] + inv2*wp[2] + inv3*wp[3] + sc;
    h_new[(size_t)n*64 + lane] = hn;

    float ev;
    if (LAYER_KIND == 0){
      float p = hn * wro0[lane];
#pragma unroll
      for (int off = 32; off >= 1; off >>= 1) p += __shfl_xor(p, off, 64);
      ev = p;
    } else {
      // LDS transpose: lane j computes p_j = sum_c hn[c]*W[c][j] (quads redundant)
      hn_l[wv][lane] = hn;
      int j = lane & 15;
      float pj = 0.0f;
#pragma unroll
      for (int c = 0; c < 64; c++)
        pj += hn_l[wv][c] * Wro1a[c*16 + j];
      float evj = silu_f(pj) * wro1b[j];
      evj += __shfl_xor(evj, 8, 64);
      evj += __shfl_xor(evj, 4, 64);
      evj += __shfl_xor(evj, 2, 64);
      evj += __shfl_xor(evj, 1, 64);
      ev = evj;
    }
    if (lane == 0) atomicAdd(&ebins[batch[n]], ev);
  }
  __syncthreads();
  if (tix < NGRP){
    float v = ebins[tix];
    if (v != 0.0f) atomicAdd(&ene[tix], v);
  }
}

// ---------------- final output convert (format matches detected input) ----------
__global__ void k_out(const float* __restrict__ ene, const int* __restrict__ flag,
                      void* __restrict__ out){
  int t = threadIdx.x;
  if (t < NGRP){
    if (*flag) ((bf16*)out)[t] = __float2bfloat16(ene[t]);
    else       ((float*)out)[t] = ene[t];
  }
}

static inline size_t rup(size_t x){ return (x + 255) & ~(size_t)255; }

extern "C" void kernel_launch(void* const* d_in, const int* in_sizes, int n_in,
                              void* d_out, int out_size, void* d_ws, size_t ws_size,
                              hipStream_t stream) {
  const void* pos   = d_in[0];
  const int*  types = (const int*)d_in[1];
  const int*  ei    = (const int*)d_in[2];
  const int*  batch = (const int*)d_in[3];
  const void* Wemb  = d_in[4];
  const void* Wr1   = d_in[5];
  const void* Wr2   = d_in[6];
  const void* Wr3   = d_in[7];
  const void* Wsc   = d_in[8];
  const void* wprod = d_in[9];
  const void* wro0  = d_in[10];
  const void* Wro1a = d_in[11];
  const void* wro1b = d_in[12];

  char* w = (char*)d_ws;
  int*   flag     = (int*)  w; w += 256;
  float* cv       = (float*)w; w += rup((size_t)CVT_N*4);
  short* swz      = (short*)w; w += rup((size_t)SWZ_N*2);
  float* ene      = (float*)w; w += 256;
  int*   deg      = (int*)  w; w += rup((size_t)N_NODES*4);
  int*   row_start= (int*)  w; w += rup((size_t)(N_NODES+1)*4);
  int*   cursor   = (int*)  w; w += rup((size_t)N_NODES*4);
  int*   sslot    = (int*)  w; w += rup((size_t)N_EDGES*4);
  int*   dslot    = (int*)  w; w += rup((size_t)N_EDGES*4);
  float* h0       = (float*)w; w += rup((size_t)N_NODES*64*4);
  float* h1       = (float*)w; w += rup((size_t)N_NODES*64*4);
  float* rbuf     = (float*)w; w += rup((size_t)N_EDGES*4);
  unsigned short* Yb = (unsigned short*)w; w += rup((size_t)N_EDGES*16*2);
  bf16*  Gb       = (bf16*) w; w += rup((size_t)N_EDGES*64*2);

  hipMemsetAsync(deg, 0, N_NODES*4, stream);
  hipMemsetAsync(ene, 0, NGRP*4, stream);

  const int* dstp = ei + N_EDGES;
  k_detect<<<1, 64, 0, stream>>>(pos, flag);
  k_cvt<<<(CVT_N + 255)/256, 256, 0, stream>>>(pos, Wemb, Wr1, Wr2, Wr3, Wsc,
                                               wprod, wro0, Wro1a, wro1b, flag, cv);
  k_swz<<<SWZ_N/256, 256, 0, stream>>>(cv, swz);
  k_hist<<<N_EDGES/256, 256, 0, stream>>>(dstp, deg);
  k_scan<<<1, 1024, 0, stream>>>(deg, row_start, cursor);
  k_fill<<<N_EDGES/256, 256, 0, stream>>>(ei, cursor, sslot, dslot);
  k_geom<<<N_EDGES/256, 256, 0, stream>>>(cv + CV_POS, sslot, dslot, Yb, rbuf);
  k_hinit<<<(N_NODES*64)/256, 256, 0, stream>>>(types, cv + CV_EMB, h0);

  float* hc = h0; float* hx = h1;
  for (int i = 0; i < NLAY; i++){
    k_mlp<<<N_EDGES/64, 256, 0, stream>>>(rbuf, swz + i*SWZ_PER_L, hc, sslot, Gb);
    if (i == 0)
      k_gu<0><<<(N_NODES*64)/256, 256, 0, stream>>>(Gb, hc, hx, Yb,
          row_start, types, cv + CV_SC + (size_t)i*NELM*4096, cv + CV_PROD + i*NELM*4,
          cv + CV_RO0, cv + CV_RO1A, cv + CV_RO1B, batch, ene);
    else
      k_gu<1><<<(N_NODES*64)/256, 256, 0, stream>>>(Gb, hc, hx, Yb,
          row_start, types, cv + CV_SC + (size_t)i*NELM*4096, cv + CV_PROD + i*NELM*4,
          cv + CV_RO0, cv + CV_RO1A, cv + CV_RO1B, batch, ene);
    float* tmp = hc; hc = hx; hx = tmp;
  }
  k_out<<<1, 64, 0, stream>>>(ene, flag, d_out);
}